// Round 12
// baseline (781.755 us; speedup 1.0000x reference)
//
#include <hip/hip_runtime.h>
#include <stdint.h>

// RoPE attention, MI355X. S=4096, HID=1024, 16 heads x 64.
// R12: KVBLK 64->32. LDS/block 64KB->33KB and VGPR capped <=85 via
// __launch_bounds__(512,6) so THREE 8-wave blocks fit per CU (24 waves, was 16).
// K LDS [32][128B] slot^=(row&15); V repacked [32 rows][128B] (d and d+32 share a
// row), slot8=(d>>5)*8+vslot, ^(d&15). Same no-max exp2 softmax, sigma-PV,
// VALU denominator, halves + LDS flash-combine as R10/R11 (passing).
// ws layout: qbf 8MB | kbf 8MB | vT 8MB | xbf 8MB | wbf 6MB | cos 512KB | sin 512KB

#define SEQLEN 4096
#define NHEAD 16
#define HDIM 64

typedef __bf16 bf16x8 __attribute__((ext_vector_type(8)));
typedef float f32x4 __attribute__((ext_vector_type(4)));
typedef float f32x16 __attribute__((ext_vector_type(16)));

__device__ __forceinline__ unsigned short f2bf(float f) {
  union { float f; unsigned int u; } v; v.f = f;
  unsigned int r = v.u + 0x7FFFu + ((v.u >> 16) & 1u);
  return (unsigned short)(r >> 16);
}
__device__ __forceinline__ unsigned int pkc(float lo, float hi) {
  union { __bf16 b[2]; unsigned int u; } z;
  z.b[0] = (__bf16)lo; z.b[1] = (__bf16)hi;
  return z.u;
}
__device__ __forceinline__ bf16x8 as_bf(uint4 v) { return __builtin_bit_cast(bf16x8, v); }
__device__ __forceinline__ f32x4 mfma16(bf16x8 a, bf16x8 b, f32x4 c) {
  return __builtin_amdgcn_mfma_f32_16x16x32_bf16(a, b, c, 0, 0, 0);
}
__device__ __forceinline__ f32x16 mfma32(bf16x8 a, bf16x8 b, f32x16 c) {
  return __builtin_amdgcn_mfma_f32_32x32x16_bf16(a, b, c, 0, 0, 0);
}
__device__ __forceinline__ uint2 mku2(unsigned x, unsigned y) {
  uint2 r; r.x = x; r.y = y; return r;
}

// ---------------- fp32 -> bf16 convert (x, then wq|wk|wv stacked) ----------------
__global__ __launch_bounds__(256) void k_convert(
    const float* __restrict__ x, const float* __restrict__ wq,
    const float* __restrict__ wk, const float* __restrict__ wv,
    unsigned short* __restrict__ xbf, unsigned short* __restrict__ wbf) {
  int i = blockIdx.x * 256 + threadIdx.x;   // one float4 per thread
  const int NX = SEQLEN * 1024 / 4;         // 1048576
  const int NW = 1024 * 1024 / 4;           // 262144 (pow2)
  float4 v;
  unsigned short* dst;
  int di;
  if (i < NX) {
    v = ((const float4*)x)[i]; dst = xbf; di = i;
  } else {
    int j = i - NX;
    const float4* src = (const float4*)((j < NW) ? wq : (j < 2 * NW) ? wk : wv);
    v = src[j & (NW - 1)];
    dst = wbf; di = j;
  }
  ushort4 o; o.x = f2bf(v.x); o.y = f2bf(v.y); o.z = f2bf(v.z); o.w = f2bf(v.w);
  ((ushort4*)dst)[di] = o;
}

// ---------------- RoPE cos/sin table (double precision) ----------------
__global__ __launch_bounds__(256) void k_table(float* __restrict__ ct, float* __restrict__ st) {
  int i = blockIdx.x * 256 + threadIdx.x;   // 4096*32 entries
  int s = i >> 5, j = i & 31;
  double inv = exp(-(double)j * 0.28782313662425572);  // ln(10000)/32
  double a = (double)s * inv;
  ct[i] = (float)cos(a);
  st[i] = (float)sin(a);
}

// ---------------- QKV GEMM (+RoPE epilogue) ----------------
__global__ __launch_bounds__(256) void k_gemm(
    const unsigned short* __restrict__ xbf, const unsigned short* __restrict__ wbf,
    const float* __restrict__ ct, const float* __restrict__ st,
    unsigned short* __restrict__ qbf, unsigned short* __restrict__ kbf,
    unsigned short* __restrict__ vT) {
  __shared__ __align__(16) unsigned short As[2][128 * 40];
  __shared__ __align__(16) unsigned short Bs[2][128 * 40];
  const int t = threadIdx.x;
  const int bn = blockIdx.x, bm = blockIdx.y;
  const int lane = t & 63, wave = t >> 6;
  const int r = lane & 15, g = lane >> 4;
  const int wm = wave >> 1, wn = wave & 1;

  const int c0 = t, c1 = t + 256;
  const int ar0 = c0 >> 2, ao0 = (c0 & 3) * 16;
  const int ar1 = c1 >> 2, ao1 = (c1 & 3) * 16;

  const char* pA0 = (const char*)xbf + (size_t)(bm * 128 + ar0) * 2048 + ao0;
  const char* pA1 = (const char*)xbf + (size_t)(bm * 128 + ar1) * 2048 + ao1;
  const char* pB0 = (const char*)wbf + (size_t)(bn * 128 + ar0) * 2048 + ao0;
  const char* pB1 = (const char*)wbf + (size_t)(bn * 128 + ar1) * 2048 + ao1;

  uint4 ra0, ra1, rb0, rb1;
#define LD_TILE                                   \
  ra0 = *(const uint4*)pA0; ra1 = *(const uint4*)pA1; \
  rb0 = *(const uint4*)pB0; rb1 = *(const uint4*)pB1; \
  pA0 += 64; pA1 += 64; pB0 += 64; pB1 += 64;

  LD_TILE
  f32x4 zero4 = {0.f, 0.f, 0.f, 0.f};
  f32x4 acc[4][4];
#pragma unroll
  for (int m = 0; m < 4; ++m)
#pragma unroll
    for (int n = 0; n < 4; ++n) acc[m][n] = zero4;

  for (int kk = 0; kk < 32; ++kk) {
    unsigned short* Ac = As[kk & 1];
    unsigned short* Bc = Bs[kk & 1];
    *(uint4*)((char*)Ac + ar0 * 80 + ao0) = ra0;
    *(uint4*)((char*)Ac + ar1 * 80 + ao1) = ra1;
    *(uint4*)((char*)Bc + ar0 * 80 + ao0) = rb0;
    *(uint4*)((char*)Bc + ar1 * 80 + ao1) = rb1;
    __syncthreads();
    if (kk < 31) { LD_TILE }
    bf16x8 af[4], bfr[4];
#pragma unroll
    for (int m = 0; m < 4; ++m)
      af[m] = as_bf(*(const uint4*)((const char*)Ac + (wm * 64 + m * 16 + r) * 80 + g * 16));
#pragma unroll
    for (int n = 0; n < 4; ++n)
      bfr[n] = as_bf(*(const uint4*)((const char*)Bc + (wn * 64 + n * 16 + r) * 80 + g * 16));
#pragma unroll
    for (int m = 0; m < 4; ++m)
#pragma unroll
      for (int n = 0; n < 4; ++n)
        acc[m][n] = mfma16(af[m], bfr[n], acc[m][n]);
  }

  const int matid = bn >> 3;  // 0=q, 1=k, 2=v
#pragma unroll
  for (int m = 0; m < 4; ++m) {
    const int row0 = bm * 128 + wm * 64 + m * 16 + 4 * g;
#pragma unroll
    for (int n = 0; n < 4; ++n) {
      const int col = bn * 128 + wn * 64 + n * 16 + r;
      const int d = col & 63;
      const int hh = (col >> 6) & 15;
      if (matid < 2) {
        const int jdx = (col >> 1) & 31;
        const float sgn = (col & 1) ? 1.0f : -1.0f;
        unsigned short* dst = (matid == 0) ? qbf : kbf;
        const float qs = (matid == 0) ? 0.18033688011112042f : 1.0f;
#pragma unroll
        for (int j = 0; j < 4; ++j) {
          float v = acc[m][n][j];
          float p = __shfl_xor(v, 1);
          int srow = row0 + j;
          float cv = ct[srow * 32 + jdx];
          float sv = st[srow * 32 + jdx];
          float o = (v * cv + p * sv * sgn) * qs;
          dst[(size_t)srow * 1024 + (hh * 64 + d)] = f2bf(o);
        }
      } else {
        ushort4 o;
        o.x = f2bf(acc[m][n][0]); o.y = f2bf(acc[m][n][1]);
        o.z = f2bf(acc[m][n][2]); o.w = f2bf(acc[m][n][3]);
        *(ushort4*)&vT[((size_t)(hh * 64 + d)) * SEQLEN + row0] = o;
      }
    }
  }
}

// ---------------- Flash attention (KVBLK=32, 3 blocks/CU) ----------------
__global__ __launch_bounds__(512, 6) void k_attn(
    const unsigned short* __restrict__ qbf, const unsigned short* __restrict__ kbf,
    const unsigned short* __restrict__ vT, float* __restrict__ out) {
  __shared__ __align__(16) char smem[33280];  // 2 halves x (K0|K1|V0|V1 4KB) + combine
  const int t = threadIdx.x;
  // XCD swizzle: 512 blocks, 8 XCDs, 64 blocks/XCD -> 2 heads per XCD
  const int b = blockIdx.x;
  const int work = (b & 7) * 64 + (b >> 3);
  const int h = work >> 5;
  const int qb = work & 31;
  const int lane = t & 63, wave = t >> 6;
  const int qw = wave & 3, hf = wave >> 2;
  const int li = lane & 31, hi = lane >> 5;
  const int q0 = qb * 128 + qw * 32;
  const int HB = hf * 16384;   // this wave's LDS half

  // Q fragments (B-operand): lane holds q = q0+li, d = c*16 + hi*8 + j. Pre-scaled.
  bf16x8 qf[4];
#pragma unroll
  for (int c = 0; c < 4; ++c)
    qf[c] = as_bf(*(const uint4*)((const char*)qbf +
              (size_t)(q0 + li) * 2048 + h * 128 + c * 32 + hi * 16));

  f32x16 z16 = {0.f};
  f32x16 acc[2];            // O^T accum: d-tile dt, row=d, col=q
  acc[0] = z16; acc[1] = z16;
  float l4[4] = {0.f, 0.f, 0.f, 0.f};

  // ---- loop-invariant LDS read addresses ----
  // K [32 rows][16 b64 slots], slot = (4c + 2hi + b0) ^ (li&15)
  const int mmK = (li & 15) ^ (hi << 1);
  int kra[4];
#pragma unroll
  for (int c = 0; c < 4; ++c)
    kra[c] = HB + li * 128 + ((((4 * c) ^ mmK)) << 3);
  // V [32 rows][16 b64 slots], slot = (dt*8 + 4kc + hi) ^ (li&15); partner ^2
  const int mmV = (li & 15) ^ hi;
  int vra[2][2];
#pragma unroll
  for (int dt = 0; dt < 2; ++dt)
#pragma unroll
    for (int kc = 0; kc < 2; ++kc)
      vra[dt][kc] = HB + 8192 + li * 128 + ((((dt * 8 + 4 * kc) ^ mmV)) << 3);

  // ---- staging addresses: per half, 256 threads ----
  const int tt = t & 255;
  const int kr = tt >> 3, c8 = tt & 7;        // K: 32 rows x 128B, 16B/thread
  const int vd = tt >> 2, c4 = tt & 3;        // V: 64 d-rows x 64B, 16B/thread
  const int wka = HB + kr * 128 + ((((2 * c8) ^ (kr & 15))) << 3);
  const int wva = HB + 8192 + (vd & 31) * 128 +
                  (((((vd >> 5) * 8 + 2 * c4) ^ (vd & 15))) << 3);

  const char* pK = (const char*)kbf + h * 128 +
                   (size_t)(hf * 2048 + kr) * 2048 + c8 * 16;
  const char* pV = (const char*)vT + (size_t)h * HDIM * SEQLEN * 2 +
                   (size_t)vd * 8192 + hf * 4096 + c4 * 16;

  uint4 rk, rv;
#define LD_KV32                                       \
  rk = *(const uint4*)pK; rv = *(const uint4*)pV;     \
  pK += 32 * 2048; pV += 64;

  LD_KV32

#pragma unroll 2
  for (int j = 0; j < 64; ++j) {
    const int JB = (j & 1) * 4096;   // compile-time after unroll-2
    // ---- stage K,V tile: 4 b64 swizzled writes ----
    *(uint2*)(smem + (wka + JB)) = mku2(rk.x, rk.y);
    *(uint2*)(smem + ((wka ^ 8) + JB)) = mku2(rk.z, rk.w);
    *(uint2*)(smem + (wva + JB)) = mku2(rv.x, rv.y);
    *(uint2*)(smem + ((wva ^ 8) + JB)) = mku2(rv.z, rv.w);
    __syncthreads();
    if (j < 63) { LD_KV32 }

    // ---- QK^T: S^T[key][q], one 32-key subtile ----
    f32x16 sT = z16;
    __builtin_amdgcn_s_setprio(1);
#pragma unroll
    for (int c = 0; c < 4; ++c) {
      uint2 a0 = *(const uint2*)(smem + (kra[c] + JB));
      uint2 a1 = *(const uint2*)(smem + ((kra[c] ^ 8) + JB));
      uint4 ku; ku.x = a0.x; ku.y = a0.y; ku.z = a1.x; ku.w = a1.y;
      sT = mfma32(as_bf(ku), qf[c], sT);
    }
    __builtin_amdgcn_s_setprio(0);

    // ---- V A-frags (sigma order) ----
    bf16x8 vf[2][2];
#pragma unroll
    for (int dt = 0; dt < 2; ++dt)
#pragma unroll
      for (int kc = 0; kc < 2; ++kc) {
        uint2 lo = *(const uint2*)(smem + (vra[dt][kc] + JB));
        uint2 hi2 = *(const uint2*)(smem + ((vra[dt][kc] ^ 16) + JB));
        uint4 vv; vv.x = lo.x; vv.y = lo.y; vv.z = hi2.x; vv.w = hi2.y;
        vf[dt][kc] = as_bf(vv);
      }

    // ---- p = exp2(raw score); bounded, no max needed ----
#pragma unroll
    for (int i = 0; i < 16; ++i) sT[i] = __builtin_amdgcn_exp2f(sT[i]);

    // ---- denominator partials (4 accumulators) ----
#pragma unroll
    for (int i = 0; i < 4; ++i)
      l4[i] += (sT[i] + sT[i + 4]) + (sT[i + 8] + sT[i + 12]);

    // ---- pack P B-frags, then 4-MFMA PV cluster ----
    bf16x8 pfr[2];
#pragma unroll
    for (int kc = 0; kc < 2; ++kc) {
      const int bix = kc * 8;
      uint4 bw;
      bw.x = pkc(sT[bix + 0], sT[bix + 1]);
      bw.y = pkc(sT[bix + 2], sT[bix + 3]);
      bw.z = pkc(sT[bix + 4], sT[bix + 5]);
      bw.w = pkc(sT[bix + 6], sT[bix + 7]);
      pfr[kc] = as_bf(bw);
    }
    __builtin_amdgcn_s_setprio(1);
#pragma unroll
    for (int kc = 0; kc < 2; ++kc) {
      acc[0] = mfma32(vf[0][kc], pfr[kc], acc[0]);
      acc[1] = mfma32(vf[1][kc], pfr[kc], acc[1]);
    }
    __builtin_amdgcn_s_setprio(0);
  }

  float lrun = (l4[0] + l4[1]) + (l4[2] + l4[3]);
  // per-half full denominator (own hi-half + partner)
  float lhalf = lrun + __shfl_xor(lrun, 32);

  // ---- flash-combine of the two KV halves via LDS (plain add; no max) ----
  __syncthreads();
  float* shm = (float*)smem;
  if (hf == 1) {
    float* ab = shm + qw * 2048;   // [64 d][32 q]
#pragma unroll
    for (int dt = 0; dt < 2; ++dt)
#pragma unroll
      for (int i = 0; i < 16; ++i) {
        int d = (i & 3) + 8 * (i >> 2) + 4 * hi + 32 * dt;
        ab[d * 32 + li] = acc[dt][i];
      }
    if (hi == 0) shm[8192 + qw * 32 + li] = lhalf;
  }
  __syncthreads();
  if (hf == 0) {
    float* ab = shm + qw * 2048;
    float l1 = shm[8192 + qw * 32 + li];
    float linv = 1.0f / (lhalf + l1);
#pragma unroll
    for (int dt = 0; dt < 2; ++dt)
#pragma unroll
      for (int i = 0; i < 16; ++i) {
        int d = (i & 3) + 8 * (i >> 2) + 4 * hi + 32 * dt;
        acc[dt][i] = (acc[dt][i] + ab[d * 32 + li]) * linv;
      }
    __asm__ volatile("" ::: "memory");

    // ---- epilogue: transpose via LDS (wave-private region), coalesced stores ----
    float* eb = shm + qw * 2048;   // [32 q][33 d-pad] floats
#pragma unroll
    for (int dt = 0; dt < 2; ++dt) {
#pragma unroll
      for (int i = 0; i < 16; ++i)
        eb[li * 33 + ((i & 3) + 8 * (i >> 2) + 4 * hi)] = acc[dt][i];
      __asm__ volatile("" ::: "memory");
#pragma unroll
      for (int it = 0; it < 16; ++it) {
        int q = it * 2 + hi;
        float v = eb[q * 33 + li];
        out[(size_t)(q0 + q) * 1024 + h * 64 + dt * 32 + li] = v;
      }
      __asm__ volatile("" ::: "memory");
    }
  }
}

extern "C" void kernel_launch(void* const* d_in, const int* in_sizes, int n_in,
                              void* d_out, int out_size, void* d_ws, size_t ws_size,
                              hipStream_t stream) {
  const float* x  = (const float*)d_in[0];
  const float* wq = (const float*)d_in[1];
  const float* wk = (const float*)d_in[2];
  const float* wv = (const float*)d_in[3];
  float* out = (float*)d_out;
  char* ws = (char*)d_ws;

  unsigned short* qbf = (unsigned short*)(ws);
  unsigned short* kbf = (unsigned short*)(ws + ((size_t)8 << 20));
  unsigned short* vT  = (unsigned short*)(ws + ((size_t)16 << 20));
  unsigned short* xbf = (unsigned short*)(ws + ((size_t)24 << 20));
  unsigned short* wbf = (unsigned short*)(ws + ((size_t)32 << 20));
  float* ct = (float*)(ws + ((size_t)38 << 20));
  float* st = (float*)(ws + ((size_t)38 << 20) + ((size_t)512 << 10));

  k_convert<<<dim3(7168), dim3(256), 0, stream>>>(x, wq, wk, wv, xbf, wbf);
  k_table<<<dim3(512), dim3(256), 0, stream>>>(ct, st);
  k_gemm<<<dim3(24, 32), dim3(256), 0, stream>>>(xbf, wbf, ct, st, qbf, kbf, vT);
  k_attn<<<dim3(512), dim3(512), 0, stream>>>(qbf, kbf, vT, out);
}

// Round 13
// 149.363 us; speedup vs baseline: 5.2339x; 5.2339x over previous
//
#include <hip/hip_runtime.h>
#include <stdint.h>

// RoPE attention, MI355X. S=4096, HID=1024, 16 heads x 64.
// R13: R12 with the launch-bounds min-waves clause REMOVED (R12's ",6" forced an
// 85-VGPR target -> f32x16 accumulators spilled to scratch -> 3GB HBM traffic).
// KVBLK=32, LDS 33280B/block -> 4 blocks/CU = 32 waves/CU (2x R11 residency).
// Same no-max exp2 softmax, sigma-PV, VALU denominator, halves + LDS combine.
// ws layout: qbf 8MB | kbf 8MB | vT 8MB | xbf 8MB | wbf 6MB | cos 512KB | sin 512KB

#define SEQLEN 4096
#define NHEAD 16
#define HDIM 64

typedef __bf16 bf16x8 __attribute__((ext_vector_type(8)));
typedef float f32x4 __attribute__((ext_vector_type(4)));
typedef float f32x16 __attribute__((ext_vector_type(16)));

__device__ __forceinline__ unsigned short f2bf(float f) {
  union { float f; unsigned int u; } v; v.f = f;
  unsigned int r = v.u + 0x7FFFu + ((v.u >> 16) & 1u);
  return (unsigned short)(r >> 16);
}
__device__ __forceinline__ unsigned int pkc(float lo, float hi) {
  union { __bf16 b[2]; unsigned int u; } z;
  z.b[0] = (__bf16)lo; z.b[1] = (__bf16)hi;
  return z.u;
}
__device__ __forceinline__ bf16x8 as_bf(uint4 v) { return __builtin_bit_cast(bf16x8, v); }
__device__ __forceinline__ f32x4 mfma16(bf16x8 a, bf16x8 b, f32x4 c) {
  return __builtin_amdgcn_mfma_f32_16x16x32_bf16(a, b, c, 0, 0, 0);
}
__device__ __forceinline__ f32x16 mfma32(bf16x8 a, bf16x8 b, f32x16 c) {
  return __builtin_amdgcn_mfma_f32_32x32x16_bf16(a, b, c, 0, 0, 0);
}
__device__ __forceinline__ uint2 mku2(unsigned x, unsigned y) {
  uint2 r; r.x = x; r.y = y; return r;
}

// ---------------- fp32 -> bf16 convert (x, then wq|wk|wv stacked) ----------------
__global__ __launch_bounds__(256) void k_convert(
    const float* __restrict__ x, const float* __restrict__ wq,
    const float* __restrict__ wk, const float* __restrict__ wv,
    unsigned short* __restrict__ xbf, unsigned short* __restrict__ wbf) {
  int i = blockIdx.x * 256 + threadIdx.x;   // one float4 per thread
  const int NX = SEQLEN * 1024 / 4;         // 1048576
  const int NW = 1024 * 1024 / 4;           // 262144 (pow2)
  float4 v;
  unsigned short* dst;
  int di;
  if (i < NX) {
    v = ((const float4*)x)[i]; dst = xbf; di = i;
  } else {
    int j = i - NX;
    const float4* src = (const float4*)((j < NW) ? wq : (j < 2 * NW) ? wk : wv);
    v = src[j & (NW - 1)];
    dst = wbf; di = j;
  }
  ushort4 o; o.x = f2bf(v.x); o.y = f2bf(v.y); o.z = f2bf(v.z); o.w = f2bf(v.w);
  ((ushort4*)dst)[di] = o;
}

// ---------------- RoPE cos/sin table (double precision) ----------------
__global__ __launch_bounds__(256) void k_table(float* __restrict__ ct, float* __restrict__ st) {
  int i = blockIdx.x * 256 + threadIdx.x;   // 4096*32 entries
  int s = i >> 5, j = i & 31;
  double inv = exp(-(double)j * 0.28782313662425572);  // ln(10000)/32
  double a = (double)s * inv;
  ct[i] = (float)cos(a);
  st[i] = (float)sin(a);
}

// ---------------- QKV GEMM (+RoPE epilogue) ----------------
__global__ __launch_bounds__(256) void k_gemm(
    const unsigned short* __restrict__ xbf, const unsigned short* __restrict__ wbf,
    const float* __restrict__ ct, const float* __restrict__ st,
    unsigned short* __restrict__ qbf, unsigned short* __restrict__ kbf,
    unsigned short* __restrict__ vT) {
  __shared__ __align__(16) unsigned short As[2][128 * 40];
  __shared__ __align__(16) unsigned short Bs[2][128 * 40];
  const int t = threadIdx.x;
  const int bn = blockIdx.x, bm = blockIdx.y;
  const int lane = t & 63, wave = t >> 6;
  const int r = lane & 15, g = lane >> 4;
  const int wm = wave >> 1, wn = wave & 1;

  const int c0 = t, c1 = t + 256;
  const int ar0 = c0 >> 2, ao0 = (c0 & 3) * 16;
  const int ar1 = c1 >> 2, ao1 = (c1 & 3) * 16;

  const char* pA0 = (const char*)xbf + (size_t)(bm * 128 + ar0) * 2048 + ao0;
  const char* pA1 = (const char*)xbf + (size_t)(bm * 128 + ar1) * 2048 + ao1;
  const char* pB0 = (const char*)wbf + (size_t)(bn * 128 + ar0) * 2048 + ao0;
  const char* pB1 = (const char*)wbf + (size_t)(bn * 128 + ar1) * 2048 + ao1;

  uint4 ra0, ra1, rb0, rb1;
#define LD_TILE                                   \
  ra0 = *(const uint4*)pA0; ra1 = *(const uint4*)pA1; \
  rb0 = *(const uint4*)pB0; rb1 = *(const uint4*)pB1; \
  pA0 += 64; pA1 += 64; pB0 += 64; pB1 += 64;

  LD_TILE
  f32x4 zero4 = {0.f, 0.f, 0.f, 0.f};
  f32x4 acc[4][4];
#pragma unroll
  for (int m = 0; m < 4; ++m)
#pragma unroll
    for (int n = 0; n < 4; ++n) acc[m][n] = zero4;

  for (int kk = 0; kk < 32; ++kk) {
    unsigned short* Ac = As[kk & 1];
    unsigned short* Bc = Bs[kk & 1];
    *(uint4*)((char*)Ac + ar0 * 80 + ao0) = ra0;
    *(uint4*)((char*)Ac + ar1 * 80 + ao1) = ra1;
    *(uint4*)((char*)Bc + ar0 * 80 + ao0) = rb0;
    *(uint4*)((char*)Bc + ar1 * 80 + ao1) = rb1;
    __syncthreads();
    if (kk < 31) { LD_TILE }
    bf16x8 af[4], bfr[4];
#pragma unroll
    for (int m = 0; m < 4; ++m)
      af[m] = as_bf(*(const uint4*)((const char*)Ac + (wm * 64 + m * 16 + r) * 80 + g * 16));
#pragma unroll
    for (int n = 0; n < 4; ++n)
      bfr[n] = as_bf(*(const uint4*)((const char*)Bc + (wn * 64 + n * 16 + r) * 80 + g * 16));
#pragma unroll
    for (int m = 0; m < 4; ++m)
#pragma unroll
      for (int n = 0; n < 4; ++n)
        acc[m][n] = mfma16(af[m], bfr[n], acc[m][n]);
  }

  const int matid = bn >> 3;  // 0=q, 1=k, 2=v
#pragma unroll
  for (int m = 0; m < 4; ++m) {
    const int row0 = bm * 128 + wm * 64 + m * 16 + 4 * g;
#pragma unroll
    for (int n = 0; n < 4; ++n) {
      const int col = bn * 128 + wn * 64 + n * 16 + r;
      const int d = col & 63;
      const int hh = (col >> 6) & 15;
      if (matid < 2) {
        const int jdx = (col >> 1) & 31;
        const float sgn = (col & 1) ? 1.0f : -1.0f;
        unsigned short* dst = (matid == 0) ? qbf : kbf;
        const float qs = (matid == 0) ? 0.18033688011112042f : 1.0f;
#pragma unroll
        for (int j = 0; j < 4; ++j) {
          float v = acc[m][n][j];
          float p = __shfl_xor(v, 1);
          int srow = row0 + j;
          float cv = ct[srow * 32 + jdx];
          float sv = st[srow * 32 + jdx];
          float o = (v * cv + p * sv * sgn) * qs;
          dst[(size_t)srow * 1024 + (hh * 64 + d)] = f2bf(o);
        }
      } else {
        ushort4 o;
        o.x = f2bf(acc[m][n][0]); o.y = f2bf(acc[m][n][1]);
        o.z = f2bf(acc[m][n][2]); o.w = f2bf(acc[m][n][3]);
        *(ushort4*)&vT[((size_t)(hh * 64 + d)) * SEQLEN + row0] = o;
      }
    }
  }
}

// ---------------- Flash attention (KVBLK=32, 4 blocks/CU = 32 waves/CU) ----------------
__global__ __launch_bounds__(512) void k_attn(
    const unsigned short* __restrict__ qbf, const unsigned short* __restrict__ kbf,
    const unsigned short* __restrict__ vT, float* __restrict__ out) {
  __shared__ __align__(16) char smem[33280];  // 2 halves x (K0|K1|V0|V1 4KB) + combine
  const int t = threadIdx.x;
  // XCD swizzle: 512 blocks, 8 XCDs, 64 blocks/XCD -> 2 heads per XCD
  const int b = blockIdx.x;
  const int work = (b & 7) * 64 + (b >> 3);
  const int h = work >> 5;
  const int qb = work & 31;
  const int lane = t & 63, wave = t >> 6;
  const int qw = wave & 3, hf = wave >> 2;
  const int li = lane & 31, hi = lane >> 5;
  const int q0 = qb * 128 + qw * 32;
  const int HB = hf * 16384;   // this wave's LDS half

  // Q fragments (B-operand): lane holds q = q0+li, d = c*16 + hi*8 + j. Pre-scaled.
  bf16x8 qf[4];
#pragma unroll
  for (int c = 0; c < 4; ++c)
    qf[c] = as_bf(*(const uint4*)((const char*)qbf +
              (size_t)(q0 + li) * 2048 + h * 128 + c * 32 + hi * 16));

  f32x16 z16 = {0.f};
  f32x16 acc[2];            // O^T accum: d-tile dt, row=d, col=q
  acc[0] = z16; acc[1] = z16;
  float l4[4] = {0.f, 0.f, 0.f, 0.f};

  // ---- loop-invariant LDS read addresses ----
  // K [32 rows][16 b64 slots], slot = (4c + 2hi + b0) ^ (li&15)
  const int mmK = (li & 15) ^ (hi << 1);
  int kra[4];
#pragma unroll
  for (int c = 0; c < 4; ++c)
    kra[c] = HB + li * 128 + ((((4 * c) ^ mmK)) << 3);
  // V [32 rows][16 b64 slots], slot = (dt*8 + 4kc + hi) ^ (li&15); partner ^2
  const int mmV = (li & 15) ^ hi;
  int vra[2][2];
#pragma unroll
  for (int dt = 0; dt < 2; ++dt)
#pragma unroll
    for (int kc = 0; kc < 2; ++kc)
      vra[dt][kc] = HB + 8192 + li * 128 + ((((dt * 8 + 4 * kc) ^ mmV)) << 3);

  // ---- staging addresses: per half, 256 threads ----
  const int tt = t & 255;
  const int kr = tt >> 3, c8 = tt & 7;        // K: 32 rows x 128B, 16B/thread
  const int vd = tt >> 2, c4 = tt & 3;        // V: 64 d-rows x 64B, 16B/thread
  const int wka = HB + kr * 128 + ((((2 * c8) ^ (kr & 15))) << 3);
  const int wva = HB + 8192 + (vd & 31) * 128 +
                  (((((vd >> 5) * 8 + 2 * c4) ^ (vd & 15))) << 3);

  const char* pK = (const char*)kbf + h * 128 +
                   (size_t)(hf * 2048 + kr) * 2048 + c8 * 16;
  const char* pV = (const char*)vT + (size_t)h * HDIM * SEQLEN * 2 +
                   (size_t)vd * 8192 + hf * 4096 + c4 * 16;

  uint4 rk, rv;
#define LD_KV32                                       \
  rk = *(const uint4*)pK; rv = *(const uint4*)pV;     \
  pK += 32 * 2048; pV += 64;

  LD_KV32

#pragma unroll 2
  for (int j = 0; j < 64; ++j) {
    const int JB = (j & 1) * 4096;   // compile-time after unroll-2
    // ---- stage K,V tile: 4 b64 swizzled writes ----
    *(uint2*)(smem + (wka + JB)) = mku2(rk.x, rk.y);
    *(uint2*)(smem + ((wka ^ 8) + JB)) = mku2(rk.z, rk.w);
    *(uint2*)(smem + (wva + JB)) = mku2(rv.x, rv.y);
    *(uint2*)(smem + ((wva ^ 8) + JB)) = mku2(rv.z, rv.w);
    __syncthreads();
    if (j < 63) { LD_KV32 }

    // ---- QK^T: S^T[key][q], one 32-key subtile ----
    f32x16 sT = z16;
    __builtin_amdgcn_s_setprio(1);
#pragma unroll
    for (int c = 0; c < 4; ++c) {
      uint2 a0 = *(const uint2*)(smem + (kra[c] + JB));
      uint2 a1 = *(const uint2*)(smem + ((kra[c] ^ 8) + JB));
      uint4 ku; ku.x = a0.x; ku.y = a0.y; ku.z = a1.x; ku.w = a1.y;
      sT = mfma32(as_bf(ku), qf[c], sT);
    }
    __builtin_amdgcn_s_setprio(0);

    // ---- V A-frags (sigma order) ----
    bf16x8 vf[2][2];
#pragma unroll
    for (int dt = 0; dt < 2; ++dt)
#pragma unroll
      for (int kc = 0; kc < 2; ++kc) {
        uint2 lo = *(const uint2*)(smem + (vra[dt][kc] + JB));
        uint2 hi2 = *(const uint2*)(smem + ((vra[dt][kc] ^ 16) + JB));
        uint4 vv; vv.x = lo.x; vv.y = lo.y; vv.z = hi2.x; vv.w = hi2.y;
        vf[dt][kc] = as_bf(vv);
      }

    // ---- p = exp2(raw score); bounded, no max needed ----
#pragma unroll
    for (int i = 0; i < 16; ++i) sT[i] = __builtin_amdgcn_exp2f(sT[i]);

    // ---- denominator partials (4 accumulators) ----
#pragma unroll
    for (int i = 0; i < 4; ++i)
      l4[i] += (sT[i] + sT[i + 4]) + (sT[i + 8] + sT[i + 12]);

    // ---- pack P B-frags, then 4-MFMA PV cluster ----
    bf16x8 pfr[2];
#pragma unroll
    for (int kc = 0; kc < 2; ++kc) {
      const int bix = kc * 8;
      uint4 bw;
      bw.x = pkc(sT[bix + 0], sT[bix + 1]);
      bw.y = pkc(sT[bix + 2], sT[bix + 3]);
      bw.z = pkc(sT[bix + 4], sT[bix + 5]);
      bw.w = pkc(sT[bix + 6], sT[bix + 7]);
      pfr[kc] = as_bf(bw);
    }
    __builtin_amdgcn_s_setprio(1);
#pragma unroll
    for (int kc = 0; kc < 2; ++kc) {
      acc[0] = mfma32(vf[0][kc], pfr[kc], acc[0]);
      acc[1] = mfma32(vf[1][kc], pfr[kc], acc[1]);
    }
    __builtin_amdgcn_s_setprio(0);
  }

  float lrun = (l4[0] + l4[1]) + (l4[2] + l4[3]);
  // per-half full denominator (own hi-half + partner)
  float lhalf = lrun + __shfl_xor(lrun, 32);

  // ---- flash-combine of the two KV halves via LDS (plain add; no max) ----
  __syncthreads();
  float* shm = (float*)smem;
  if (hf == 1) {
    float* ab = shm + qw * 2048;   // [64 d][32 q]
#pragma unroll
    for (int dt = 0; dt < 2; ++dt)
#pragma unroll
      for (int i = 0; i < 16; ++i) {
        int d = (i & 3) + 8 * (i >> 2) + 4 * hi + 32 * dt;
        ab[d * 32 + li] = acc[dt][i];
      }
    if (hi == 0) shm[8192 + qw * 32 + li] = lhalf;
  }
  __syncthreads();
  if (hf == 0) {
    float* ab = shm + qw * 2048;
    float l1 = shm[8192 + qw * 32 + li];
    float linv = 1.0f / (lhalf + l1);
#pragma unroll
    for (int dt = 0; dt < 2; ++dt)
#pragma unroll
      for (int i = 0; i < 16; ++i) {
        int d = (i & 3) + 8 * (i >> 2) + 4 * hi + 32 * dt;
        acc[dt][i] = (acc[dt][i] + ab[d * 32 + li]) * linv;
      }
    __asm__ volatile("" ::: "memory");

    // ---- epilogue: transpose via LDS (wave-private region), coalesced stores ----
    float* eb = shm + qw * 2048;   // [32 q][33 d-pad] floats
#pragma unroll
    for (int dt = 0; dt < 2; ++dt) {
#pragma unroll
      for (int i = 0; i < 16; ++i)
        eb[li * 33 + ((i & 3) + 8 * (i >> 2) + 4 * hi)] = acc[dt][i];
      __asm__ volatile("" ::: "memory");
#pragma unroll
      for (int it = 0; it < 16; ++it) {
        int q = it * 2 + hi;
        float v = eb[q * 33 + li];
        out[(size_t)(q0 + q) * 1024 + h * 64 + dt * 32 + li] = v;
      }
      __asm__ volatile("" ::: "memory");
    }
  }
}

extern "C" void kernel_launch(void* const* d_in, const int* in_sizes, int n_in,
                              void* d_out, int out_size, void* d_ws, size_t ws_size,
                              hipStream_t stream) {
  const float* x  = (const float*)d_in[0];
  const float* wq = (const float*)d_in[1];
  const float* wk = (const float*)d_in[2];
  const float* wv = (const float*)d_in[3];
  float* out = (float*)d_out;
  char* ws = (char*)d_ws;

  unsigned short* qbf = (unsigned short*)(ws);
  unsigned short* kbf = (unsigned short*)(ws + ((size_t)8 << 20));
  unsigned short* vT  = (unsigned short*)(ws + ((size_t)16 << 20));
  unsigned short* xbf = (unsigned short*)(ws + ((size_t)24 << 20));
  unsigned short* wbf = (unsigned short*)(ws + ((size_t)32 << 20));
  float* ct = (float*)(ws + ((size_t)38 << 20));
  float* st = (float*)(ws + ((size_t)38 << 20) + ((size_t)512 << 10));

  k_convert<<<dim3(7168), dim3(256), 0, stream>>>(x, wq, wk, wv, xbf, wbf);
  k_table<<<dim3(512), dim3(256), 0, stream>>>(ct, st);
  k_gemm<<<dim3(24, 32), dim3(256), 0, stream>>>(xbf, wbf, ct, st, qbf, kbf, vT);
  k_attn<<<dim3(512), dim3(512), 0, stream>>>(qbf, kbf, vT, out);
}